// Round 9
// baseline (123.775 us; speedup 1.0000x reference)
//
#include <hip/hip_runtime.h>
#include <hip/hip_bf16.h>
#include <hip/hip_cooperative_groups.h>

namespace cg = cooperative_groups;

// Conv2dKan, fused MFMA kernel. b=16, cin=cout=64, H=W=32, K=3, PAD=1, BASIS=8.
// out[b,o,pix] = bias[o] + sum_{i,k,s8} Wt[i,k,o,s]*act(x[b,i,pix+off(k)])[s]
//   Wt[...,0]=w, Wt[...,s]=w*c[s] (s=1..7) bf16, layout [i][kpos][o][s]
//   act(x) = [silu(x), T1..T7(tanh x)] bf16; act(pad) = act(0) = [0,0,-1,0,1,0,-1,0]
//   bias[o] = sum_{i,k} w*c[...,0]  (T0==1)
// R25 = R22 main body (74.9us; 32x32x16 MFMA read-once Wt, xlds halo, dbuf act
//   scratch, 1024thr 1blk/CU) MERGED WITH PREP into ONE COOPERATIVE KERNEL:
//   - 9 structural variants (occupancy 8-32 w/CU, LDS traffic 2x, MFMA shape,
//     barrier domains) all land 74-80us -> main is pipe-insensitive; the only
//     untouched cost is the 2-kernel serial launch structure (~5-10us launch +
//     prep->main drain bubble per rocprof.md).
//   - grid 256 x 1024thr = exactly 1 block/CU (co-residency: LDS 104448B,
//     16 waves, VGPR<=128 by __launch_bounds__(1024,4)).
//   - Phase A (distributed prep): 144 Wt triples/block (8 bf16 each); bias on
//     blocks 0..63 (wave-0 reduce); 16KB/block x-prefetch (4MB total, warms
//     L3 in parallel with Wt-prep instead of serialized behind it).
//   - cg::this_grid().sync(): device-scope fence -> Wt/bias visible across
//     XCDs (the sanctioned mechanism per guide G16).
//   - Then R22 body verbatim (single-variable change: launch merge only).
//   32x32 layouts (HW-verified R21/R22): C/D col=lane&31(pix),
//   row=(reg&3)+8*(reg>>2)+4*(lane>>5); A row=lane&31(o), k=(lane>>5)*8+s;
//   B col=lane&31(pix), k=(lane>>5)*8+s.

#define CIN   64
#define COUT  64
#define HW    32
#define LL    1024
#define NS    8

typedef __attribute__((ext_vector_type(8))) short short8;
typedef __attribute__((ext_vector_type(16))) float f32x16;

// ws layout (bytes):
//   [0)       Wt    : 64*9*64*8 bf16 = 589824 B   ([i][kpos][o][s])
//   [589824)  bias  : 64 f32         = 256 B

// grid 256 = (16 b x 16 row-pairs), block 1024 = 16 waves = (kq8 x om2).
// Wave: 64pix (both rows) x 32o (tile om) x 8ch.
__global__ __launch_bounds__(1024, 4) void kan_all_kernel(
        const float* __restrict__ x,
        const float* __restrict__ w,
        const float* __restrict__ c,
        __hip_bfloat16* __restrict__ Wt,
        float* __restrict__ bias,
        float* __restrict__ out) {
    // ushort units:
    //   [0,     17408): xlds  — float x[ch64][pos136] (zero-padded 4x34 halo), 34816 B
    //   [17408, 34816): act scratch buf0 [kq8][pos136][chl2] x 16B
    //   [34816, 52224): act scratch buf1
    // epilogue overlay: float red[kq8][pix64][o 33pad] = 67584 B (xlds+buf0 only)
    __shared__ __align__(16) unsigned short Wlds[52224];   // 104448 B -> 1 block/CU

    const int tid = threadIdx.x;
    const int bid = blockIdx.x;

    // ================= phase A: distributed prep =================
    // A1: Wt — 144 (i,k,o) triples per block, 8 bf16 each (covers 36864 total)
    if (tid < 144) {
        const int e = bid * 144 + tid;            // == (i*9+k)*64+o
        const int i = e / (9 * COUT);
        const int r = e - i * 9 * COUT;
        const int k = r / COUT;
        const int o = r - k * COUT;
        const int widx = (i * COUT + o) * 9 + k;
        const float wval = w[widx];
        __hip_bfloat16* dst = Wt + (size_t)e * NS;
        dst[0] = __float2bfloat16(wval);
#pragma unroll
        for (int s = 1; s < 8; ++s) dst[s] = __float2bfloat16(wval * c[widx * 8 + s]);
    }
    // A2: bias — blocks 0..63 (one o each), wave-0 64-lane reduce over i
    if (bid < 64 && tid < 64) {
        const int o = bid;
        const int i = tid;
        float v = 0.f;
#pragma unroll
        for (int k = 0; k < 9; ++k) {
            const int idx = (i * COUT + o) * 9 + k;
            v += w[idx] * c[idx * 8];
        }
#pragma unroll
        for (int off = 32; off > 0; off >>= 1) v += __shfl_down(v, off);
        if (i == 0) bias[o] = v;
    }
    // A3: x prefetch — 16KB/block (4MB total) warms L3 under A1/A2
    {
        const float4 v = ((const float4*)x)[bid * 1024 + tid];
        const float a = v.x + v.y + v.z + v.w;
        __asm__ volatile("" :: "v"(a));           // keep-alive, no DCE
    }

    cg::this_grid().sync();   // Wt/bias visible device-wide (cross-XCD fence)

    // ================= main: R22 body =================
    const int wvid = tid >> 6;        // 0..15
    const int lane = tid & 63;
    const int l31  = lane & 31;
    const int half = lane >> 5;       // K-step channel half
    const int kq   = wvid >> 1;       // K-eighth: channels [kq*8, kq*8+8)
    const int om   = wvid & 1;        // o-tile: [om*32, om*32+32)

    const int b    = bid >> 4;
    const int row0 = (bid & 15) << 1; // first of the 2 output rows

    const unsigned short* WtU = (const unsigned short*)Wt;
    float* xf = (float*)Wlds;         // xlds

    // ---- preload x halo: 64ch x 4rows x 34cols = 8704 cells, coalesced ----
#pragma unroll
    for (int p = 0; p < 9; ++p) {
        const int cell = p * 1024 + tid;
        if (cell < 8704) {
            const int ch  = cell / 136;
            const int pos = cell - ch * 136;
            const int r4  = pos / 34;                 // halo row 0..3
            const int col = pos - r4 * 34;
            const int gy  = row0 - 1 + r4;
            const int gx  = col - 1;
            float v = 0.f;   // border -> x=0 -> act computes exactly the pad vector
            if ((unsigned)gy < 32u && (unsigned)gx < 32u)
                v = x[((size_t)(b * CIN + ch) * HW + gy) * HW + gx];
            xf[cell] = v;                             // cell == ch*136 + pos
        }
    }
    __syncthreads();

    f32x16 acc0, acc1;                // pixel rows 0 and 1 (same o-tile om)
#pragma unroll
    for (int r = 0; r < 16; ++r) { acc0[r] = 0.f; acc1[r] = 0.f; }

    // lane-invariant Wt base: i = kq*8 + half (+chunk*2), o = om*32 + l31
    const size_t wlane = ((size_t)(kq * 8 + half) * 9 * COUT + om * 32 + l31) * NS;

    for (int chunk = 0; chunk < 4; ++chunk) {
        unsigned short* ubuf = Wlds + 17408 + (chunk & 1) * 17408;

        // ---- act: 2176 cells (16 ch x 136 pos); cells tid, tid+1024, tid+2048<128.
        //      cell = kqc*272 + pos*2 + chl, channel = kqc*8 + chunk*2 + chl ----
        auto doCell = [&](int cell) {
            const int kqc = cell / 272;
            const int rr  = cell - kqc * 272;
            const int chl = rr & 1;
            const int pos = rr >> 1;                 // 0..135
            const float xv = xf[(kqc * 8 + chunk * 2 + chl) * 136 + pos];
            const float e   = __expf(xv);                         // one exp
            const float sig = e * __builtin_amdgcn_rcpf(1.f + e);
            const float res = xv * sig;                           // silu
            const float t   = 1.f - 2.f * __builtin_amdgcn_rcpf(__builtin_fmaf(e, e, 1.f)); // tanh
            const float t2  = t + t;
            const float T2 = __builtin_fmaf(t2, t,  -1.f);
            const float T3 = __builtin_fmaf(t2, T2, -t);
            const float T4 = __builtin_fmaf(t2, T3, -T2);
            const float T5 = __builtin_fmaf(t2, T4, -T3);
            const float T6 = __builtin_fmaf(t2, T5, -T4);
            const float T7 = __builtin_fmaf(t2, T6, -T5);
            union { __hip_bfloat162 h2[4]; float4 f4; } U;
            U.h2[0] = __float22bfloat162_rn(make_float2(res, t));
            U.h2[1] = __float22bfloat162_rn(make_float2(T2, T3));
            U.h2[2] = __float22bfloat162_rn(make_float2(T4, T5));
            U.h2[3] = __float22bfloat162_rn(make_float2(T6, T7));
            *(float4*)(ubuf + cell * 8) = U.f4;
        };
        doCell(tid);
        doCell(tid + 1024);
        if (tid < 128) doCell(tid + 2048);

        __syncthreads();   // scratch buf[chunk&1] ready; xlds reads done

        // ---- MFMA: one K-step (2ch x 8s) x 9 kpos; wf read ONCE, feeds both rows ----
        const unsigned short* afb = ubuf + kq * 2176;          // [pos136][chl2] x 8
        const unsigned short* wc  = WtU + wlane + (size_t)chunk * 9216; // +2ch
#pragma unroll
        for (int kpos = 0; kpos < 9; ++kpos) {
            const int posb = (kpos / 3) * 34 + (kpos % 3);
            short8 af0 = *(const short8*)(afb + ((posb      + l31) * 2 + half) * 8);
            short8 af1 = *(const short8*)(afb + ((posb + 34 + l31) * 2 + half) * 8);
            short8 wf  = *(const short8*)(wc + kpos * 512);
            acc0 = __builtin_amdgcn_mfma_f32_32x32x16_bf16(wf, af0, acc0, 0, 0, 0);
            acc1 = __builtin_amdgcn_mfma_f32_32x32x16_bf16(wf, af1, acc1, 0, 0, 0);
        }
    }

    // ---- epilogue: reduce 8 K-eighth partials, two o-rounds of 32 (round h
    //      written by om==h waves; both accs = both pixel rows).
    //      red (67584B) overlays xlds+buf0 only; chunk-3 MFMA read buf1, and
    //      xlds/buf0 readers were fenced by the chunk-3 act barrier. ----
    float* red = (float*)Wlds;       // red[kq8][pix64][33]
#pragma unroll
    for (int h = 0; h < 2; ++h) {
        if (h) __syncthreads();      // round-0 reads done before overwrite
        if (om == h) {
#pragma unroll
            for (int r = 0; r < 16; ++r) {
                const int ol = (r & 3) + 8 * (r >> 2) + 4 * half;   // o within tile
                red[(kq * 64 +      l31) * 33 + ol] = acc0[r];      // row 0, pix 0..31
                red[(kq * 64 + 32 + l31) * 33 + ol] = acc1[r];      // row 1, pix 32..63
            }
        }
        __syncthreads();
#pragma unroll
        for (int rep = 0; rep < 2; ++rep) {
            const int v  = rep * 1024 + tid;   // 2048 = 64 pix x 32 o
            const int p  = v & 63;
            const int ol = v >> 6;
            float s = bias[h * 32 + ol];
#pragma unroll
            for (int kqq = 0; kqq < 8; ++kqq)
                s += red[(kqq * 64 + p) * 33 + ol];
            out[(size_t)(b * COUT + h * 32 + ol) * LL + (row0 + (p >> 5)) * HW + (p & 31)] = s;
        }
    }
}

extern "C" void kernel_launch(void* const* d_in, const int* in_sizes, int n_in,
                              void* d_out, int out_size, void* d_ws, size_t ws_size,
                              hipStream_t stream) {
    const float* x = (const float*)d_in[0];
    const float* w = (const float*)d_in[1];
    const float* c = (const float*)d_in[2];
    float* out = (float*)d_out;

    char* ws = (char*)d_ws;
    __hip_bfloat16* Wt   = (__hip_bfloat16*)(ws);
    float*          bias = (float*)(ws + 589824);

    void* args[] = {(void*)&x, (void*)&w, (void*)&c, (void*)&Wt, (void*)&bias, (void*)&out};
    hipLaunchCooperativeKernel((void*)kan_all_kernel, dim3(256), dim3(1024),
                               args, 0, stream);
}

// Round 10
// 75.015 us; speedup vs baseline: 1.6500x; 1.6500x over previous
//
#include <hip/hip_runtime.h>
#include <hip/hip_bf16.h>

// Conv2dKan, fused MFMA kernel. b=16, cin=cout=64, H=W=32, K=3, PAD=1, BASIS=8.
// out[b,o,pix] = bias[o] + sum_{i,k,s8} Wt[i,k,o,s]*act(x[b,i,pix+off(k)])[s]
//   Wt[...,0]=w, Wt[...,s]=w*c[s] (s=1..7) bf16, layout [i][kpos][o][s]
//   act(x) = [silu(x), T1..T7(tanh x)] bf16; act(pad) = act(0) = [0,0,-1,0,1,0,-1,0]
//   bias[o] = sum_{i,k} w*c[...,0]  (T0==1)
// R26 = R22 (74.9us best; 32x32x16 MFMA, read-once Wt, xlds halo, dbuf scratch,
//   1024thr 1blk/CU, 2-kernel launch) + ONE CHANGE, counter-evidenced by R25's
//   first-ever main-body PMC capture (SQ_LDS_BANK_CONFLICT=856K):
//   SCRATCH LAYOUT [kq8][pos136][chl2] -> [kq8][chl2][pos136] (ch-major).
//   - R22's af read ((posb+l31)*2+half)*16B had 32B/lane stride -> 32 lanes on
//     4 banks = 8-way conflict (~2.9x per m136), sitting on the barrier-bounded
//     MFMA dependency path. New read afb+half*1088 + (posb+l31)*16B has 16B
//     stride -> all 32 banks covered -> conflict-free.
//   - Channel mapping unchanged: g=kq*2+chl -> ch = kq*8+chunk*2+chl; act
//     writes stay cell-contiguous; xlds reads stay stride-1; epilogue already
//     conflict-free (stride-33). Fragments bit-identical to R22.
//   - R25's coop merge REVERTED (coop launch + grid.sync + 256-block prep cost
//     >> the launch gap it removed: 123.8us).
//   32x32 layouts (HW-verified R21/R22): C/D col=lane&31(pix),
//   row=(reg&3)+8*(reg>>2)+4*(lane>>5); A row=lane&31(o), k=(lane>>5)*8+s;
//   B col=lane&31(pix), k=(lane>>5)*8+s.
//   LDS 104448 B -> 1 block/CU, 16 waves/CU. Epilogue: 8 kq-partials reduced in
//   2 o-rounds via red[kq8][pix64][33] = 67584 B overlaying xlds+buf0 only.

#define CIN   64
#define COUT  64
#define HW    32
#define LL    1024
#define NS    8

typedef __attribute__((ext_vector_type(8))) short short8;
typedef __attribute__((ext_vector_type(16))) float f32x16;

// ws layout (bytes):
//   [0)       Wt    : 64*9*64*8 bf16 = 589824 B   ([i][kpos][o][s])
//   [589824)  bias  : 64 f32         = 256 B
//   [590080)  dummy : keep-alive sink for prefetch

__global__ void prep_kernel(const float* __restrict__ w,
                            const float* __restrict__ c,
                            __hip_bfloat16* __restrict__ Wt,
                            float* __restrict__ bias,
                            const float* __restrict__ x,
                            float* __restrict__ dummy) {
    const int bx = blockIdx.x;
    if (bx < 144) {
        // Wt part
        const int tid = bx * 256 + threadIdx.x;   // < 36864 = 64i*9k*64o
        const int i = tid / (9 * COUT);
        const int r = tid - i * 9 * COUT;
        const int k = r / COUT;
        const int o = r - k * COUT;
        const int widx = (i * COUT + o) * 9 + k;
        const float wv = w[widx];
        __hip_bfloat16* dst = Wt + (size_t)tid * NS;   // tid == (i*9+k)*64+o
        dst[0] = __float2bfloat16(wv);
#pragma unroll
        for (int s = 1; s < 8; ++s) dst[s] = __float2bfloat16(wv * c[widx * 8 + s]);
        return;
    }
    if (bx < 208) {
        // bias part: 64 blocks, one o each; 64-lane wave reduce over i.
        const int o = bx - 144;
        const int i = threadIdx.x;
        if (i >= 64) return;
        float v = 0.f;
#pragma unroll
        for (int k = 0; k < 9; ++k) {
            const int idx = (i * COUT + o) * 9 + k;
            v += w[idx] * c[idx * 8];
        }
#pragma unroll
        for (int off = 32; off > 0; off >>= 1) v += __shfl_down(v, off);
        if (i == 0) bias[o] = v;
        return;
    }
    // x-prefetch part: 1024 blocks, each touches one (b,ch) 4KB image -> L3/L2 warm.
    const int idx = bx - 208;          // [0,1024)
    const int r  = idx & 7;
    const int m  = idx >> 3;
    const int b  = r + 8 * (m & 1);
    const int ch = m >> 1;
    const float4 v = ((const float4*)(x + (size_t)(b * CIN + ch) * LL))[threadIdx.x];
    const float acc = v.x + v.y + v.z + v.w;
    if (acc == 1.0e-37f) dummy[threadIdx.x] = acc;   // keep-alive; never taken in practice
}

// grid (16 b, 16 row-pairs), block 1024 = 16 waves = (kq8 x om2).
// Wave: 64pix (both rows) x 32o (tile om) x 8ch.
__global__ __launch_bounds__(1024, 4) void kan_fused_kernel(
        const float* __restrict__ x,
        const __hip_bfloat16* __restrict__ Wt,
        const float* __restrict__ bias,
        float* __restrict__ out) {
    // ushort units:
    //   [0,     17408): xlds  — float x[ch64][pos136] (zero-padded 4x34 halo), 34816 B
    //   [17408, 34816): act scratch buf0 [kq8][chl2][pos136] x 16B  (ch-major!)
    //   [34816, 52224): act scratch buf1
    // epilogue overlay: float red[kq8][pix64][o 33pad] = 67584 B (xlds+buf0 only)
    __shared__ __align__(16) unsigned short Wlds[52224];   // 104448 B -> 1 block/CU

    const int tid  = threadIdx.x;
    const int wv   = tid >> 6;        // 0..15
    const int lane = tid & 63;
    const int l31  = lane & 31;
    const int half = lane >> 5;       // K-step channel half
    const int kq   = wv >> 1;         // K-eighth: channels [kq*8, kq*8+8)
    const int om   = wv & 1;          // o-tile: [om*32, om*32+32)

    const int b    = blockIdx.x;
    const int row0 = blockIdx.y << 1; // first of the 2 output rows

    const unsigned short* WtU = (const unsigned short*)Wt;
    float* xf = (float*)Wlds;         // xlds

    // ---- preload x halo: 64ch x 4rows x 34cols = 8704 cells, coalesced ----
#pragma unroll
    for (int p = 0; p < 9; ++p) {
        const int cell = p * 1024 + tid;
        if (cell < 8704) {
            const int ch  = cell / 136;
            const int pos = cell - ch * 136;
            const int r4  = pos / 34;                 // halo row 0..3
            const int col = pos - r4 * 34;
            const int gy  = row0 - 1 + r4;
            const int gx  = col - 1;
            float v = 0.f;   // border -> x=0 -> act computes exactly the pad vector
            if ((unsigned)gy < 32u && (unsigned)gx < 32u)
                v = x[((size_t)(b * CIN + ch) * HW + gy) * HW + gx];
            xf[cell] = v;                             // cell == ch*136 + pos
        }
    }
    __syncthreads();

    f32x16 acc0, acc1;                // pixel rows 0 and 1 (same o-tile om)
#pragma unroll
    for (int r = 0; r < 16; ++r) { acc0[r] = 0.f; acc1[r] = 0.f; }

    // lane-invariant Wt base: i = kq*8 + half (+chunk*2), o = om*32 + l31
    const size_t wlane = ((size_t)(kq * 8 + half) * 9 * COUT + om * 32 + l31) * NS;

    for (int chunk = 0; chunk < 4; ++chunk) {
        unsigned short* ubuf = Wlds + 17408 + (chunk & 1) * 17408;

        // ---- act: 2176 cells, ch-major: cell = g*136 + pos, g = kq*2+chl;
        //      channel = (g>>1)*8 + chunk*2 + (g&1). Writes cell-contiguous. ----
        auto doCell = [&](int cell) {
            const int g   = cell / 136;
            const int pos = cell - g * 136;          // 0..135
            const float xv = xf[((g >> 1) * 8 + chunk * 2 + (g & 1)) * 136 + pos];
            const float e   = __expf(xv);                         // one exp
            const float sig = e * __builtin_amdgcn_rcpf(1.f + e);
            const float res = xv * sig;                           // silu
            const float t   = 1.f - 2.f * __builtin_amdgcn_rcpf(__builtin_fmaf(e, e, 1.f)); // tanh
            const float t2  = t + t;
            const float T2 = __builtin_fmaf(t2, t,  -1.f);
            const float T3 = __builtin_fmaf(t2, T2, -t);
            const float T4 = __builtin_fmaf(t2, T3, -T2);
            const float T5 = __builtin_fmaf(t2, T4, -T3);
            const float T6 = __builtin_fmaf(t2, T5, -T4);
            const float T7 = __builtin_fmaf(t2, T6, -T5);
            union { __hip_bfloat162 h2[4]; float4 f4; } U;
            U.h2[0] = __float22bfloat162_rn(make_float2(res, t));
            U.h2[1] = __float22bfloat162_rn(make_float2(T2, T3));
            U.h2[2] = __float22bfloat162_rn(make_float2(T4, T5));
            U.h2[3] = __float22bfloat162_rn(make_float2(T6, T7));
            *(float4*)(ubuf + cell * 8) = U.f4;
        };
        doCell(tid);
        doCell(tid + 1024);
        if (tid < 128) doCell(tid + 2048);

        __syncthreads();   // scratch buf[chunk&1] ready; xlds reads done

        // ---- MFMA: af reads now 16B/lane stride -> conflict-free; wf read
        //      ONCE from global L2, feeds both rows ----
        const unsigned short* afb = ubuf + (kq * 2 + half) * 1088;   // [pos136] x 16B
        const unsigned short* wc  = WtU + wlane + (size_t)chunk * 9216; // +2ch
#pragma unroll
        for (int kpos = 0; kpos < 9; ++kpos) {
            const int posb = (kpos / 3) * 34 + (kpos % 3);
            short8 af0 = *(const short8*)(afb + (posb      + l31) * 8);
            short8 af1 = *(const short8*)(afb + (posb + 34 + l31) * 8);
            short8 wf  = *(const short8*)(wc + kpos * 512);
            acc0 = __builtin_amdgcn_mfma_f32_32x32x16_bf16(wf, af0, acc0, 0, 0, 0);
            acc1 = __builtin_amdgcn_mfma_f32_32x32x16_bf16(wf, af1, acc1, 0, 0, 0);
        }
    }

    // ---- epilogue: reduce 8 K-eighth partials, two o-rounds of 32 (round h
    //      written by om==h waves; both accs = both pixel rows).
    //      red (67584B) overlays xlds+buf0 only; chunk-3 MFMA read buf1, and
    //      xlds/buf0 readers were fenced by the chunk-3 act barrier. ----
    float* red = (float*)Wlds;       // red[kq8][pix64][33]
#pragma unroll
    for (int h = 0; h < 2; ++h) {
        if (h) __syncthreads();      // round-0 reads done before overwrite
        if (om == h) {
#pragma unroll
            for (int r = 0; r < 16; ++r) {
                const int ol = (r & 3) + 8 * (r >> 2) + 4 * half;   // o within tile
                red[(kq * 64 +      l31) * 33 + ol] = acc0[r];      // row 0, pix 0..31
                red[(kq * 64 + 32 + l31) * 33 + ol] = acc1[r];      // row 1, pix 32..63
            }
        }
        __syncthreads();
#pragma unroll
        for (int rep = 0; rep < 2; ++rep) {
            const int v  = rep * 1024 + tid;   // 2048 = 64 pix x 32 o
            const int p  = v & 63;
            const int ol = v >> 6;
            float s = bias[h * 32 + ol];
#pragma unroll
            for (int kqq = 0; kqq < 8; ++kqq)
                s += red[(kqq * 64 + p) * 33 + ol];
            out[(size_t)(b * COUT + h * 32 + ol) * LL + (row0 + (p >> 5)) * HW + (p & 31)] = s;
        }
    }
}

extern "C" void kernel_launch(void* const* d_in, const int* in_sizes, int n_in,
                              void* d_out, int out_size, void* d_ws, size_t ws_size,
                              hipStream_t stream) {
    const float* x = (const float*)d_in[0];
    const float* w = (const float*)d_in[1];
    const float* c = (const float*)d_in[2];
    float* out = (float*)d_out;

    char* ws = (char*)d_ws;
    __hip_bfloat16* Wt    = (__hip_bfloat16*)(ws);
    float*          bias  = (float*)(ws + 589824);
    float*          dummy = (float*)(ws + 590080);

    // 144 Wt + 64 bias + 1024 x-prefetch = 1232 blocks, all parallel
    prep_kernel<<<1232, 256, 0, stream>>>(w, c, Wt, bias, x, dummy);
    kan_fused_kernel<<<dim3(16, 16), 1024, 0, stream>>>(x, Wt, bias, out);
}